// Round 6
// baseline (866.040 us; speedup 1.0000x reference)
//
#include <hip/hip_runtime.h>
#include <hip/hip_fp16.h>

#define BLK 256
#define BSHIFT 6              // 64 dst nodes per bucket
#define BNODES 64
#define BMASK 63
#define NREG 8                // per-bucket sub-regions (XCD-privatization heuristic)
#define CAP2 512              // entries per (bucket, region); mean 256, >15 sigma margin
#define MAXE (NREG * CAP2)    // 4096 max staged edges per bucket

static inline int cdiv(int a, int b) { return (a + b - 1) / b; }

// ---------------- bucket append, XCD-private regions ----------------
__global__ void k_bucket(const int* __restrict__ src, const int* __restrict__ dst,
                         int* __restrict__ cursor, int* __restrict__ slab, int e) {
    int i = blockIdx.x * blockDim.x + threadIdx.x;
    if (i >= e) return;
    int s = src[i];
    int d = dst[i];
    int b = d >> BSHIFT;
    int c = b * NREG + (blockIdx.x & (NREG - 1));   // region private to this XCD (heuristic)
    int pos = atomicAdd(&cursor[c], 1);
    if (pos < CAP2) slab[(size_t)c * CAP2 + pos] = (s << BSHIFT) | (d & BMASK);
}

// ---------------- per-bucket degree count -> dinv ----------------
__global__ void k_bdeg(const int* __restrict__ cursor, const int* __restrict__ slab,
                       float* __restrict__ dinv, int n) {
    __shared__ int cnt[BNODES];
    int tid = threadIdx.x;
    if (tid < BNODES) cnt[tid] = 0;
    __syncthreads();
    int b = blockIdx.x;
#pragma unroll
    for (int r = 0; r < NREG; ++r) {
        int c = b * NREG + r;
        int m = min(cursor[c], CAP2);
        const int* sl = slab + (size_t)c * CAP2;
        for (int i = tid; i < m; i += BLK) atomicAdd(&cnt[sl[i] & BMASK], 1);
    }
    __syncthreads();
    int nd = b * BNODES + tid;
    if (tid < BNODES && nd < n)
        dinv[nd] = rsqrtf((float)cnt[tid] + 1.0f);
}

// ---------------- fused: feature encode -> @W0 -> *dinv -> Hs[n,16] (f16) ----------------
__global__ void k_featmm(const int* __restrict__ feat,
                         const float* __restrict__ emb_user,
                         const float* __restrict__ emb_known,
                         const float* __restrict__ w_user,
                         const float* __restrict__ b_user,
                         const float* __restrict__ emb_cat,
                         const float* __restrict__ w_cat,
                         const float* __restrict__ b_cat,
                         const float* __restrict__ w0,
                         const float* __restrict__ dinv,
                         __half* __restrict__ Hs,
                         int n, int user_max, int cat_max) {
    __shared__ float w0s[8 * 16];
    for (int t = threadIdx.x; t < 8 * 16; t += blockDim.x) w0s[t] = w0[t];
    __syncthreads();
    int i = blockIdx.x * blockDim.x + threadIdx.x;
    if (i >= n) return;
    int col0 = feat[i * 3 + 0];
    int col1 = feat[i * 3 + 1];
    int typ  = feat[i * 3 + 2];
    float x[8];
    if (typ == 0) {
        int u = min(max(col0, 0), user_max);
        int k = min(max(col1, 0), 1);
        float in[8];
#pragma unroll
        for (int d = 0; d < 8; ++d) {
            float v = emb_user[u * 8 + d] + emb_known[k * 8 + d];
            in[d] = v > 0.f ? v : 0.f;
        }
#pragma unroll
        for (int c = 0; c < 8; ++c) {
            float s = b_user[c];
#pragma unroll
            for (int d = 0; d < 8; ++d) s += in[d] * w_user[d * 8 + c];
            x[c] = s;
        }
    } else {
        int ci = min(max(col0, 0), cat_max);
        float in[4];
#pragma unroll
        for (int d = 0; d < 4; ++d) {
            float v = emb_cat[ci * 4 + d];
            in[d] = v > 0.f ? v : 0.f;
        }
#pragma unroll
        for (int c = 0; c < 8; ++c) {
            float s = b_cat[c];
#pragma unroll
            for (int d = 0; d < 4; ++d) s += in[d] * w_cat[d * 8 + c];
            x[c] = s;
        }
    }
    float dv = dinv[i];
    float o[16];
#pragma unroll
    for (int c = 0; c < 16; ++c) {
        float s = 0.f;
#pragma unroll
        for (int d = 0; d < 8; ++d) s += x[d] * w0s[d * 16 + c];
        o[c] = s * dv;
    }
    union { __half2 h[8]; uint4 u[2]; } pk;
#pragma unroll
    for (int k = 0; k < 8; ++k) pk.h[k] = __floats2half2_rn(o[2 * k], o[2 * k + 1]);
    uint4* dp = reinterpret_cast<uint4*>(Hs + (size_t)i * 16);
    dp[0] = pk.u[0];
    dp[1] = pk.u[1];
}

// ---------------- 8-deep-MLP gather loop (shared by both bconv kernels) ----------------
// Each of 128 lane-pairs owns edge slots {base + k*128 + g}; lane q in {0,1} owns
// 8 of the 16 channels. Phase 1 issues 8 independent global loads; phase 2 does
// the dependent LDS atomics — keeps ~8 gathers in flight per wave.
__device__ __forceinline__ void gather_loop(const int* __restrict__ eds, int mtot,
                                            const uint4* __restrict__ Hs4,
                                            float (*acc)[17], int tid) {
    int g = tid >> 1, q = tid & 1;
    for (int base = 0; base < mtot; base += 8 * 128) {
        uint4 v[8];
        int u[8];
#pragma unroll
        for (int k = 0; k < 8; ++k) {
            int idx = base + k * 128 + g;
            u[k] = (idx < mtot) ? eds[idx] : -1;
            if (u[k] >= 0) v[k] = Hs4[(size_t)(u[k] >> BSHIFT) * 2 + q];
        }
#pragma unroll
        for (int k = 0; k < 8; ++k) {
            if (u[k] >= 0) {
                int dl = u[k] & BMASK;
                union { uint4 u4; __half2 h[4]; } c;
                c.u4 = v[k];
#pragma unroll
                for (int j = 0; j < 4; ++j) {
                    float2 f = __half22float2(c.h[j]);
                    atomicAdd(&acc[dl][8 * q + 2 * j + 0], f.x);
                    atomicAdd(&acc[dl][8 * q + 2 * j + 1], f.y);
                }
            }
        }
    }
}

// ---------------- conv1: staged-LDS gather + finalize + fused @W2*dinv -> Hs2 (f16) ----------------
__global__ void __launch_bounds__(BLK, 4)
k_bconv1(const int* __restrict__ cursor, const int* __restrict__ slab,
         const __half* __restrict__ Hs, const float* __restrict__ dinv,
         const float* __restrict__ b0, const float* __restrict__ w2,
         __half* __restrict__ Hs2, int n) {
    __shared__ float acc[BNODES][17];
    __shared__ int eds[MAXE];
    __shared__ float w2s[16 * 16];
    __shared__ float b0s[16];
    int tid = threadIdx.x;
    for (int t = tid; t < BNODES * 17; t += BLK) ((float*)acc)[t] = 0.f;
    w2s[tid] = w2[tid];          // BLK == 256 == 16*16
    if (tid < 16) b0s[tid] = b0[tid];
    int b = blockIdx.x;
    int mtot = 0;
#pragma unroll
    for (int r = 0; r < NREG; ++r) {
        int m = min(cursor[b * NREG + r], CAP2);
        const int* sl = slab + (size_t)(b * NREG + r) * CAP2;
        for (int i = tid; i < m; i += BLK) eds[mtot + i] = sl[i];
        mtot += m;
    }
    __syncthreads();
    gather_loop(eds, mtot, reinterpret_cast<const uint4*>(Hs), acc, tid);
    __syncthreads();
    int nd = b * BNODES + tid;
    if (tid < BNODES && nd < n) {
        float dv = dinv[nd];
        const __half* hrow = Hs + (size_t)nd * 16;
        float h1[16];
#pragma unroll
        for (int c = 0; c < 16; ++c) {
            float v = dv * (acc[tid][c] + __half2float(hrow[c])) + b0s[c];
            h1[c] = v > 0.f ? v : 0.f;
        }
        float o[16];
#pragma unroll
        for (int c2 = 0; c2 < 16; ++c2) {
            float sum = 0.f;
#pragma unroll
            for (int c = 0; c < 16; ++c) sum += h1[c] * w2s[c * 16 + c2];
            o[c2] = sum * dv;
        }
        union { __half2 h[8]; uint4 u[2]; } pk;
#pragma unroll
        for (int k = 0; k < 8; ++k) pk.h[k] = __floats2half2_rn(o[2 * k], o[2 * k + 1]);
        uint4* dp = reinterpret_cast<uint4*>(Hs2 + (size_t)nd * 16);
        dp[0] = pk.u[0];
        dp[1] = pk.u[1];
    }
}

// ---------------- conv2: staged-LDS gather + finalize + fused heads -> out ----------------
__global__ void __launch_bounds__(BLK, 4)
k_bconv2(const int* __restrict__ cursor, const int* __restrict__ slab,
         const __half* __restrict__ Hs, const float* __restrict__ dinv,
         const float* __restrict__ b2,
         const float* __restrict__ w_mem, const float* __restrict__ b_mem,
         const float* __restrict__ w_node, const float* __restrict__ b_node,
         float* __restrict__ out, int n) {
    __shared__ float acc[BNODES][17];
    __shared__ int eds[MAXE];
    __shared__ float wms[16], wn0[16], wn1[16], b2s[16];
    int tid = threadIdx.x;
    for (int t = tid; t < BNODES * 17; t += BLK) ((float*)acc)[t] = 0.f;
    if (tid < 16) {
        wms[tid] = w_mem[tid];
        wn0[tid] = w_node[tid * 2 + 0];
        wn1[tid] = w_node[tid * 2 + 1];
        b2s[tid] = b2[tid];
    }
    int b = blockIdx.x;
    int mtot = 0;
#pragma unroll
    for (int r = 0; r < NREG; ++r) {
        int m = min(cursor[b * NREG + r], CAP2);
        const int* sl = slab + (size_t)(b * NREG + r) * CAP2;
        for (int i = tid; i < m; i += BLK) eds[mtot + i] = sl[i];
        mtot += m;
    }
    __syncthreads();
    gather_loop(eds, mtot, reinterpret_cast<const uint4*>(Hs), acc, tid);
    __syncthreads();
    int nd = b * BNODES + tid;
    if (tid < BNODES && nd < n) {
        float dv = dinv[nd];
        const __half* hrow = Hs + (size_t)nd * 16;
        float mph = b_mem[0];
        float n0 = b_node[0];
        float n1 = b_node[1];
#pragma unroll
        for (int c = 0; c < 16; ++c) {
            float v = dv * (acc[tid][c] + __half2float(hrow[c])) + b2s[c];
            float h = v > 0.f ? v : 0.f;
            mph += h * wms[c];
            n0  += h * wn0[c];
            n1  += h * wn1[c];
        }
        out[nd] = mph;
        out[n + 2 * nd + 0] = n0;
        out[n + 2 * nd + 1] = n1;
    }
}

extern "C" void kernel_launch(void* const* d_in, const int* in_sizes, int n_in,
                              void* d_out, int out_size, void* d_ws, size_t ws_size,
                              hipStream_t stream) {
    const int*   edges     = (const int*)d_in[0];
    const int*   feat      = (const int*)d_in[1];
    const float* emb_user  = (const float*)d_in[2];
    const float* emb_known = (const float*)d_in[3];
    const float* w_user    = (const float*)d_in[4];
    const float* b_user    = (const float*)d_in[5];
    const float* emb_cat   = (const float*)d_in[6];
    const float* w_cat     = (const float*)d_in[7];
    const float* b_cat     = (const float*)d_in[8];
    const float* w0        = (const float*)d_in[9];
    const float* b0        = (const float*)d_in[10];
    const float* w2        = (const float*)d_in[11];
    const float* b2        = (const float*)d_in[12];
    const float* w_node    = (const float*)d_in[13];
    const float* b_node    = (const float*)d_in[14];
    const float* w_mem     = (const float*)d_in[15];
    const float* b_mem     = (const float*)d_in[16];

    const int E = in_sizes[0] / 2;
    const int n = in_sizes[1] / 3;
    const int user_max = in_sizes[2] / 8 - 1;
    const int cat_max  = in_sizes[6] / 4 - 1;
    const int B = cdiv(n, BNODES);

    const int* src = edges;
    const int* dst = edges + E;

    // workspace layout
    __half* hsA = (__half*)d_ws;                      // 16n halfs (3.2 MB)
    __half* hsB = hsA + (size_t)n * 16;               // 16n halfs
    float* dinv = (float*)(hsB + (size_t)n * 16);     // n floats
    int* cursor = (int*)(dinv + n);                   // B*NREG
    int* slab   = cursor + (size_t)B * NREG;          // B*NREG*CAP2 (~25.6 MB)

    float* outp = (float*)d_out;

    hipMemsetAsync(cursor, 0, (size_t)B * NREG * sizeof(int), stream);
    k_bucket<<<cdiv(E, BLK), BLK, 0, stream>>>(src, dst, cursor, slab, E);
    k_bdeg<<<B, BLK, 0, stream>>>(cursor, slab, dinv, n);
    k_featmm<<<cdiv(n, BLK), BLK, 0, stream>>>(feat, emb_user, emb_known, w_user, b_user,
                                               emb_cat, w_cat, b_cat, w0, dinv, hsA,
                                               n, user_max, cat_max);
    k_bconv1<<<B, BLK, 0, stream>>>(cursor, slab, hsA, dinv, b0, w2, hsB, n);
    k_bconv2<<<B, BLK, 0, stream>>>(cursor, slab, hsB, dinv, b2,
                                    w_mem, b_mem, w_node, b_node, outp, n);
}

// Round 7
// 315.077 us; speedup vs baseline: 2.7487x; 2.7487x over previous
//
#include <hip/hip_runtime.h>
#include <hip/hip_fp16.h>

#define BLK 256
#define BSHIFT 6              // 64 dst nodes per bucket
#define BNODES 64
#define BMASK 63
#define NREG 8                // per-bucket sub-regions (XCD-privatization heuristic)
#define CAP2 512              // entries per (bucket, region); mean 256, >15 sigma margin
#define MAXE (NREG * CAP2)    // 4096 max staged edges per bucket
#define FXS 1048576.0f        // 2^20 fixed-point scale for LDS int accumulation
#define FXI (1.0f / 1048576.0f)

static inline int cdiv(int a, int b) { return (a + b - 1) / b; }

// ---------------- bucket append, XCD-private regions ----------------
__global__ void k_bucket(const int* __restrict__ src, const int* __restrict__ dst,
                         int* __restrict__ cursor, int* __restrict__ slab, int e) {
    int i = blockIdx.x * blockDim.x + threadIdx.x;
    if (i >= e) return;
    int s = src[i];
    int d = dst[i];
    int b = d >> BSHIFT;
    int c = b * NREG + (blockIdx.x & (NREG - 1));   // region private to this XCD (heuristic)
    int pos = atomicAdd(&cursor[c], 1);
    if (pos < CAP2) slab[(size_t)c * CAP2 + pos] = (s << BSHIFT) | (d & BMASK);
}

// ---------------- per-bucket degree count -> dinv ----------------
__global__ void k_bdeg(const int* __restrict__ cursor, const int* __restrict__ slab,
                       float* __restrict__ dinv, int n) {
    __shared__ int cnt[BNODES];
    int tid = threadIdx.x;
    if (tid < BNODES) cnt[tid] = 0;
    __syncthreads();
    int b = blockIdx.x;
#pragma unroll
    for (int r = 0; r < NREG; ++r) {
        int c = b * NREG + r;
        int m = min(cursor[c], CAP2);
        const int* sl = slab + (size_t)c * CAP2;
        for (int i = tid; i < m; i += BLK) atomicAdd(&cnt[sl[i] & BMASK], 1);
    }
    __syncthreads();
    int nd = b * BNODES + tid;
    if (tid < BNODES && nd < n)
        dinv[nd] = rsqrtf((float)cnt[tid] + 1.0f);
}

// ---------------- fused: feature encode -> @W0 -> *dinv -> Hs[n,16] (f16) ----------------
__global__ void k_featmm(const int* __restrict__ feat,
                         const float* __restrict__ emb_user,
                         const float* __restrict__ emb_known,
                         const float* __restrict__ w_user,
                         const float* __restrict__ b_user,
                         const float* __restrict__ emb_cat,
                         const float* __restrict__ w_cat,
                         const float* __restrict__ b_cat,
                         const float* __restrict__ w0,
                         const float* __restrict__ dinv,
                         __half* __restrict__ Hs,
                         int n, int user_max, int cat_max) {
    __shared__ float w0s[8 * 16];
    for (int t = threadIdx.x; t < 8 * 16; t += blockDim.x) w0s[t] = w0[t];
    __syncthreads();
    int i = blockIdx.x * blockDim.x + threadIdx.x;
    if (i >= n) return;
    int col0 = feat[i * 3 + 0];
    int col1 = feat[i * 3 + 1];
    int typ  = feat[i * 3 + 2];
    float x[8];
    if (typ == 0) {
        int u = min(max(col0, 0), user_max);
        int k = min(max(col1, 0), 1);
        float in[8];
#pragma unroll
        for (int d = 0; d < 8; ++d) {
            float v = emb_user[u * 8 + d] + emb_known[k * 8 + d];
            in[d] = v > 0.f ? v : 0.f;
        }
#pragma unroll
        for (int c = 0; c < 8; ++c) {
            float s = b_user[c];
#pragma unroll
            for (int d = 0; d < 8; ++d) s += in[d] * w_user[d * 8 + c];
            x[c] = s;
        }
    } else {
        int ci = min(max(col0, 0), cat_max);
        float in[4];
#pragma unroll
        for (int d = 0; d < 4; ++d) {
            float v = emb_cat[ci * 4 + d];
            in[d] = v > 0.f ? v : 0.f;
        }
#pragma unroll
        for (int c = 0; c < 8; ++c) {
            float s = b_cat[c];
#pragma unroll
            for (int d = 0; d < 4; ++d) s += in[d] * w_cat[d * 8 + c];
            x[c] = s;
        }
    }
    float dv = dinv[i];
    float o[16];
#pragma unroll
    for (int c = 0; c < 16; ++c) {
        float s = 0.f;
#pragma unroll
        for (int d = 0; d < 8; ++d) s += x[d] * w0s[d * 16 + c];
        o[c] = s * dv;
    }
    union { __half2 h[8]; uint4 u[2]; } pk;
#pragma unroll
    for (int k = 0; k < 8; ++k) pk.h[k] = __floats2half2_rn(o[2 * k], o[2 * k + 1]);
    uint4* dp = reinterpret_cast<uint4*>(Hs + (size_t)i * 16);
    dp[0] = pk.u[0];
    dp[1] = pk.u[1];
}

// ---------------- 8-deep gather loop, fixed-point int LDS accumulation ----------------
// acc is int[BNODES][17]; each add is a native ds_add_u32 (no fp CAS loop).
__device__ __forceinline__ void gather_loop(const int* __restrict__ eds, int mtot,
                                            const uint4* __restrict__ Hs4,
                                            int (*acc)[17], int tid) {
    int g = tid >> 1, q = tid & 1;
    for (int base = 0; base < mtot; base += 8 * 128) {
        uint4 v[8];
        int u[8];
#pragma unroll
        for (int k = 0; k < 8; ++k) {
            int idx = base + k * 128 + g;
            u[k] = (idx < mtot) ? eds[idx] : -1;
            if (u[k] >= 0) v[k] = Hs4[(size_t)(u[k] >> BSHIFT) * 2 + q];
        }
#pragma unroll
        for (int k = 0; k < 8; ++k) {
            if (u[k] >= 0) {
                int dl = u[k] & BMASK;
                union { uint4 u4; __half2 h[4]; } c;
                c.u4 = v[k];
#pragma unroll
                for (int j = 0; j < 4; ++j) {
                    float2 f = __half22float2(c.h[j]);
                    atomicAdd(&acc[dl][8 * q + 2 * j + 0], __float2int_rn(f.x * FXS));
                    atomicAdd(&acc[dl][8 * q + 2 * j + 1], __float2int_rn(f.y * FXS));
                }
            }
        }
    }
}

// ---------------- conv1: staged-LDS gather + finalize + fused @W2*dinv -> Hs2 (f16) ----------------
__global__ void __launch_bounds__(BLK, 4)
k_bconv1(const int* __restrict__ cursor, const int* __restrict__ slab,
         const __half* __restrict__ Hs, const float* __restrict__ dinv,
         const float* __restrict__ b0, const float* __restrict__ w2,
         __half* __restrict__ Hs2, int n) {
    __shared__ int acc[BNODES][17];
    __shared__ int eds[MAXE];
    __shared__ float w2s[16 * 16];
    __shared__ float b0s[16];
    int tid = threadIdx.x;
    for (int t = tid; t < BNODES * 17; t += BLK) ((int*)acc)[t] = 0;
    w2s[tid] = w2[tid];          // BLK == 256 == 16*16
    if (tid < 16) b0s[tid] = b0[tid];
    int b = blockIdx.x;
    int mtot = 0;
#pragma unroll
    for (int r = 0; r < NREG; ++r) {
        int m = min(cursor[b * NREG + r], CAP2);
        const int* sl = slab + (size_t)(b * NREG + r) * CAP2;
        for (int i = tid; i < m; i += BLK) eds[mtot + i] = sl[i];
        mtot += m;
    }
    __syncthreads();
    gather_loop(eds, mtot, reinterpret_cast<const uint4*>(Hs), acc, tid);
    __syncthreads();
    int nd = b * BNODES + tid;
    if (tid < BNODES && nd < n) {
        float dv = dinv[nd];
        const __half* hrow = Hs + (size_t)nd * 16;
        float h1[16];
#pragma unroll
        for (int c = 0; c < 16; ++c) {
            float v = dv * ((float)acc[tid][c] * FXI + __half2float(hrow[c])) + b0s[c];
            h1[c] = v > 0.f ? v : 0.f;
        }
        float o[16];
#pragma unroll
        for (int c2 = 0; c2 < 16; ++c2) {
            float sum = 0.f;
#pragma unroll
            for (int c = 0; c < 16; ++c) sum += h1[c] * w2s[c * 16 + c2];
            o[c2] = sum * dv;
        }
        union { __half2 h[8]; uint4 u[2]; } pk;
#pragma unroll
        for (int k = 0; k < 8; ++k) pk.h[k] = __floats2half2_rn(o[2 * k], o[2 * k + 1]);
        uint4* dp = reinterpret_cast<uint4*>(Hs2 + (size_t)nd * 16);
        dp[0] = pk.u[0];
        dp[1] = pk.u[1];
    }
}

// ---------------- conv2: staged-LDS gather + finalize + fused heads -> out ----------------
__global__ void __launch_bounds__(BLK, 4)
k_bconv2(const int* __restrict__ cursor, const int* __restrict__ slab,
         const __half* __restrict__ Hs, const float* __restrict__ dinv,
         const float* __restrict__ b2,
         const float* __restrict__ w_mem, const float* __restrict__ b_mem,
         const float* __restrict__ w_node, const float* __restrict__ b_node,
         float* __restrict__ out, int n) {
    __shared__ int acc[BNODES][17];
    __shared__ int eds[MAXE];
    __shared__ float wms[16], wn0[16], wn1[16], b2s[16];
    int tid = threadIdx.x;
    for (int t = tid; t < BNODES * 17; t += BLK) ((int*)acc)[t] = 0;
    if (tid < 16) {
        wms[tid] = w_mem[tid];
        wn0[tid] = w_node[tid * 2 + 0];
        wn1[tid] = w_node[tid * 2 + 1];
        b2s[tid] = b2[tid];
    }
    int b = blockIdx.x;
    int mtot = 0;
#pragma unroll
    for (int r = 0; r < NREG; ++r) {
        int m = min(cursor[b * NREG + r], CAP2);
        const int* sl = slab + (size_t)(b * NREG + r) * CAP2;
        for (int i = tid; i < m; i += BLK) eds[mtot + i] = sl[i];
        mtot += m;
    }
    __syncthreads();
    gather_loop(eds, mtot, reinterpret_cast<const uint4*>(Hs), acc, tid);
    __syncthreads();
    int nd = b * BNODES + tid;
    if (tid < BNODES && nd < n) {
        float dv = dinv[nd];
        const __half* hrow = Hs + (size_t)nd * 16;
        float mph = b_mem[0];
        float n0 = b_node[0];
        float n1 = b_node[1];
#pragma unroll
        for (int c = 0; c < 16; ++c) {
            float v = dv * ((float)acc[tid][c] * FXI + __half2float(hrow[c])) + b2s[c];
            float h = v > 0.f ? v : 0.f;
            mph += h * wms[c];
            n0  += h * wn0[c];
            n1  += h * wn1[c];
        }
        out[nd] = mph;
        out[n + 2 * nd + 0] = n0;
        out[n + 2 * nd + 1] = n1;
    }
}

extern "C" void kernel_launch(void* const* d_in, const int* in_sizes, int n_in,
                              void* d_out, int out_size, void* d_ws, size_t ws_size,
                              hipStream_t stream) {
    const int*   edges     = (const int*)d_in[0];
    const int*   feat      = (const int*)d_in[1];
    const float* emb_user  = (const float*)d_in[2];
    const float* emb_known = (const float*)d_in[3];
    const float* w_user    = (const float*)d_in[4];
    const float* b_user    = (const float*)d_in[5];
    const float* emb_cat   = (const float*)d_in[6];
    const float* w_cat     = (const float*)d_in[7];
    const float* b_cat     = (const float*)d_in[8];
    const float* w0        = (const float*)d_in[9];
    const float* b0        = (const float*)d_in[10];
    const float* w2        = (const float*)d_in[11];
    const float* b2        = (const float*)d_in[12];
    const float* w_node    = (const float*)d_in[13];
    const float* b_node    = (const float*)d_in[14];
    const float* w_mem     = (const float*)d_in[15];
    const float* b_mem     = (const float*)d_in[16];

    const int E = in_sizes[0] / 2;
    const int n = in_sizes[1] / 3;
    const int user_max = in_sizes[2] / 8 - 1;
    const int cat_max  = in_sizes[6] / 4 - 1;
    const int B = cdiv(n, BNODES);

    const int* src = edges;
    const int* dst = edges + E;

    // workspace layout
    __half* hsA = (__half*)d_ws;                      // 16n halfs (3.2 MB)
    __half* hsB = hsA + (size_t)n * 16;               // 16n halfs
    float* dinv = (float*)(hsB + (size_t)n * 16);     // n floats
    int* cursor = (int*)(dinv + n);                   // B*NREG
    int* slab   = cursor + (size_t)B * NREG;          // B*NREG*CAP2 (~25.6 MB)

    float* outp = (float*)d_out;

    hipMemsetAsync(cursor, 0, (size_t)B * NREG * sizeof(int), stream);
    k_bucket<<<cdiv(E, BLK), BLK, 0, stream>>>(src, dst, cursor, slab, E);
    k_bdeg<<<B, BLK, 0, stream>>>(cursor, slab, dinv, n);
    k_featmm<<<cdiv(n, BLK), BLK, 0, stream>>>(feat, emb_user, emb_known, w_user, b_user,
                                               emb_cat, w_cat, b_cat, w0, dinv, hsA,
                                               n, user_max, cat_max);
    k_bconv1<<<B, BLK, 0, stream>>>(cursor, slab, hsA, dinv, b0, w2, hsB, n);
    k_bconv2<<<B, BLK, 0, stream>>>(cursor, slab, hsB, dinv, b2,
                                    w_mem, b_mem, w_node, b_node, outp, n);
}